// Round 7
// baseline (1290.780 us; speedup 1.0000x reference)
//
#include <hip/hip_runtime.h>
#include <math.h>
#include <stdint.h>

typedef float f32x4 __attribute__((ext_vector_type(4)));
typedef short short8 __attribute__((ext_vector_type(8)));

static constexpr int HWo   = 3136;   // 56*56
static constexpr int NB    = 8;
static constexpr int NP    = 3200;   // padded pixel rows per batch (25*128)
static constexpr int KDIM  = 1794;   // 1792 + 2 coord channels
static constexpr int KP1   = 1856;   // gemm1 K padded to 29*64
static constexpr int ODIM  = 1792;   // gemm2 K = 28*64
static constexpr int NCENT = 3136;
static constexpr int NPC   = 3328;   // centroid rows padded to 13*256 for 256-tile gemm2
static constexpr int NHB   = 49;     // valid 64-centroid half-blocks (3136/64), partial stride

__device__ __forceinline__ uint16_t f2bf(float f) {
  union { float f; uint32_t u; } v; v.f = f;
  uint32_t u = v.u;
  return (uint16_t)((u + 0x7FFFu + ((u >> 16) & 1u)) >> 16);   // RNE
}
__device__ __forceinline__ float bf2f(uint16_t h) {
  union { uint32_t u; float f; } v; v.u = ((uint32_t)h) << 16;
  return v.f;
}

// async global->LDS, 16B per lane; LDS dest is wave-uniform base + lane*16
__device__ __forceinline__ void gld16(const uint16_t* __restrict__ g, uint16_t* l) {
  __builtin_amdgcn_global_load_lds(
      (const __attribute__((address_space(1))) uint16_t*)g,
      (__attribute__((address_space(3))) uint16_t*)l,
      16, 0, 0);
}

// bijective XCD-chunk swizzle (m204)
__device__ __forceinline__ int xcd_swizzle(int bid, int nwg) {
  int q = nwg >> 3, r = nwg & 7;
  int xcd = bid & 7, idx = bid >> 3;
  int base = (xcd < r) ? xcd * (q + 1) : r * (q + 1) + (xcd - r) * q;
  return base + idx;
}

// ---------------- one-time converts ----------------
__global__ __launch_bounds__(256) void convW_kernel(const float* __restrict__ W, uint16_t* __restrict__ Wh) {
  int idx = blockIdx.x * 256 + threadIdx.x;          // 1792*1856 exact
  int o = idx / KP1, k = idx % KP1;
  float v = (k < KDIM) ? W[(size_t)o * KDIM + k] : 0.f;
  Wh[idx] = f2bf(v);
}

// C [1792][3136] f32 -> Ct [3328][1792] bf16 rows 0..3135 (tail zero-filled separately)
__global__ __launch_bounds__(256) void convC_kernel(const float* __restrict__ C, uint16_t* __restrict__ Ct) {
  __shared__ float tile[64][65];
  int bj = blockIdx.x * 64;          // centroid block (49)
  int bo = blockIdx.y * 64;          // channel block  (28)
  int tx = threadIdx.x & 63, ty = threadIdx.x >> 6;
  #pragma unroll
  for (int s = 0; s < 16; ++s) {
    int o = ty + s * 4;
    tile[o][tx] = C[(size_t)(bo + o) * NCENT + bj + tx];
  }
  __syncthreads();
  #pragma unroll
  for (int s = 0; s < 16; ++s) {
    int j = ty + s * 4;
    Ct[(size_t)(bj + j) * ODIM + bo + tx] = f2bf(tile[tx][j]);
  }
}

// ---------------- row squared-norms of a bf16 [*][1792] matrix (Ct -> cent) ----------------
__global__ __launch_bounds__(256) void rownorm_kernel(const uint16_t* __restrict__ src, float* __restrict__ dst) {
  int t = threadIdx.x, lane = t & 63, wave = t >> 6;
  int row = blockIdx.x * 4 + wave;
  const uint32_t* p = (const uint32_t*)(src + (size_t)row * ODIM);
  float s = 0.f;
  #pragma unroll
  for (int it = 0; it < 14; ++it) {
    uint32_t u = p[it * 64 + lane];
    float a = bf2f((uint16_t)(u & 0xFFFF)), b = bf2f((uint16_t)(u >> 16));
    s += a * a + b * b;
  }
  #pragma unroll
  for (int m = 1; m < 64; m <<= 1) s += __shfl_xor(s, m, 64);
  if (lane == 0) dst[row] = s;
}

// ---------------- zero-fill (graph-capture-safe) ----------------
__global__ __launch_bounds__(256) void zerof_kernel(float* __restrict__ p, int n) {
  int i = blockIdx.x * 256 + threadIdx.x;
  if (i < n) p[i] = 0.f;
}

// ---------------- pooling (all 3 levels, native res, fp32), batched on blockIdx.y ----------------
static constexpr int P1SZ = 256 * 3136;   // 802816
static constexpr int P2SZ = 512 * 784;    // 401408
static constexpr int P3SZ = 1024 * 196;   // 200704
static constexpr int PTOT = P1SZ + P2SZ + P3SZ;      // 1404928

__device__ __forceinline__ float pool9f(const float* __restrict__ p, int S, int y, int x) {
  float s = 0.f;
  for (int dy = -1; dy <= 1; ++dy) {
    int yy = y + dy; if (yy < 0 || yy >= S) continue;
    for (int dx = -1; dx <= 1; ++dx) {
      int xx = x + dx; if (xx < 0 || xx >= S) continue;
      s += p[yy * S + xx];
    }
  }
  return s * (1.f / 9.f);
}

__global__ __launch_bounds__(256) void pool_kernel(const float* __restrict__ p1, const float* __restrict__ p2,
                                                   const float* __restrict__ p3, float* __restrict__ pooled, int g0) {
  int b = g0 + blockIdx.y;
  float* pb = pooled + (size_t)blockIdx.y * PTOT;
  int idx = blockIdx.x * 256 + threadIdx.x;
  const float* src; int S, loc;
  if (idx < P1SZ)              { src = p1 + (size_t)b * P1SZ; S = 56; loc = idx; }
  else if (idx < P1SZ + P2SZ)  { src = p2 + (size_t)b * P2SZ; S = 28; loc = idx - P1SZ; }
  else                         { src = p3 + (size_t)b * P3SZ; S = 14; loc = idx - P1SZ - P2SZ; }
  int c = loc / (S * S), hw = loc % (S * S);
  pb[idx] = pool9f(src + (size_t)c * S * S, S, hw / S, hw % S);
}

// ---------------- assemble xcb bf16 [bg*3200 + 3136][1856] pixel-major ----------------
__global__ __launch_bounds__(256) void assemble_kernel(const float* __restrict__ pooled, uint16_t* __restrict__ xcb) {
  int bg = blockIdx.y;
  const float* pb = pooled + (size_t)bg * PTOT;
  uint16_t* xb = xcb + (size_t)bg * NP * KP1;
  int idx = blockIdx.x * 256 + threadIdx.x;
  int i = idx / KP1, ch = idx % KP1;
  int x = i % 56, y = i / 56;
  float v;
  if (ch < 256) {
    v = pb[ch * 3136 + i];
  } else if (ch < 1792) {
    const float* base; int S; float scale, shift;
    if (ch < 768) { base = pb + P1SZ + (ch - 256) * 784;          S = 28; scale = 0.5f;  shift = -0.25f;  }
    else          { base = pb + P1SZ + P2SZ + (ch - 768) * 196;   S = 14; scale = 0.25f; shift = -0.375f; }
    float sx = x * scale + shift, sy = y * scale + shift;
    float fx0 = floorf(sx), fy0 = floorf(sy);
    float fx = sx - fx0, fy = sy - fy0;
    int x0 = (int)fx0, y0 = (int)fy0, x1 = x0 + 1, y1 = y0 + 1;
    x0 = x0 < 0 ? 0 : x0; x1 = x1 > S - 1 ? S - 1 : x1;
    y0 = y0 < 0 ? 0 : y0; y1 = y1 > S - 1 ? S - 1 : y1;
    float v00 = base[y0 * S + x0], v01 = base[y0 * S + x1];
    float v10 = base[y1 * S + x0], v11 = base[y1 * S + x1];
    v = (1.f - fy) * ((1.f - fx) * v00 + fx * v01) + fy * ((1.f - fx) * v10 + fx * v11);
  } else if (ch == 1792) v = -1.f + 2.f * x / 55.f;
  else if (ch == 1793)   v = -1.f + 2.f * y / 55.f;
  else                   v = 0.f;                    // K padding: MUST be zero
  xb[idx] = f2bf(v);
}

// ---------------- MFMA GEMM1 (m97 2-barrier) + LDS-transpose epilogue + fused rownorm ----------------
__global__ __launch_bounds__(256) void gemm1_mfma(const uint16_t* __restrict__ Wh, const float* __restrict__ bias,
                                                  const uint16_t* __restrict__ xcb, uint16_t* __restrict__ phi_t,
                                                  float* __restrict__ feat) {
  __shared__ union { uint16_t ab[2][128][64]; uint16_t tr[128][136]; } sm;
  int wid = xcd_swizzle(blockIdx.x, gridDim.x);
  int row0 = (wid % 14) * 128;       // o block (fast axis)
  int col0 = (wid / 14) * 128;       // pixel block (global incl. group)
  int t = threadIdx.x;
  int lane = t & 63, wave = t >> 6;
  int wm = wave & 1, wn = wave >> 1;
  int l15 = lane & 15, quad = lane >> 4;
  int rr = wave * 8 + (lane >> 3);
  int sg = ((lane & 7) ^ (lane >> 3)) * 8;
  f32x4 acc[4][4] = {};
  for (int k0 = 0; k0 < KP1; k0 += 64) {
    #pragma unroll
    for (int i = 0; i < 4; ++i) {
      gld16(&Wh [(size_t)(row0 + i * 32 + rr) * KP1 + k0 + sg], &sm.ab[0][i * 32 + wave * 8][0]);
      gld16(&xcb[(size_t)(col0 + i * 32 + rr) * KP1 + k0 + sg], &sm.ab[1][i * 32 + wave * 8][0]);
    }
    __syncthreads();
    #pragma unroll
    for (int kk = 0; kk < 2; ++kk) {
      short8 a[4], b[4];
      #pragma unroll
      for (int i = 0; i < 4; ++i) {
        int r = wm * 64 + i * 16 + l15;
        a[i] = *(const short8*)&sm.ab[0][r][((quad + 4 * kk) ^ (r & 7)) * 8];
      }
      #pragma unroll
      for (int j = 0; j < 4; ++j) {
        int r = wn * 64 + j * 16 + l15;
        b[j] = *(const short8*)&sm.ab[1][r][((quad + 4 * kk) ^ (r & 7)) * 8];
      }
      #pragma unroll
      for (int i = 0; i < 4; ++i)
        #pragma unroll
        for (int j = 0; j < 4; ++j)
          acc[i][j] = __builtin_amdgcn_mfma_f32_16x16x32_bf16(a[i], b[j], acc[i][j], 0, 0, 0);
    }
    __syncthreads();
  }
  #pragma unroll
  for (int i = 0; i < 4; ++i) {
    int o4 = wm * 64 + i * 16 + quad * 4;
    float4 bv = *(const float4*)&bias[row0 + o4];
    #pragma unroll
    for (int j = 0; j < 4; ++j) {
      int p = wn * 64 + j * 16 + l15;
      ushort4 u;
      u.x = f2bf(acc[i][j][0] + bv.x);
      u.y = f2bf(acc[i][j][1] + bv.y);
      u.z = f2bf(acc[i][j][2] + bv.z);
      u.w = f2bf(acc[i][j][3] + bv.w);
      *(ushort4*)&sm.tr[p][o4] = u;
    }
  }
  __syncthreads();
  int c = t & 15, prb = t >> 4;
  #pragma unroll
  for (int s = 0; s < 8; ++s) {
    int pr = s * 16 + prb;
    uint4 v = *(const uint4*)&sm.tr[pr][c * 8];
    *(uint4*)&phi_t[(size_t)(col0 + pr) * ODIM + row0 + c * 8] = v;
    const uint16_t* pv = (const uint16_t*)&v;
    float ssq = 0.f;
    #pragma unroll
    for (int e = 0; e < 8; ++e) { float f = bf2f(pv[e]); ssq += f * f; }
    #pragma unroll
    for (int m = 1; m < 16; m <<= 1) ssq += __shfl_xor(ssq, m, 16);
    if (c == 0) atomicAdd(&feat[col0 + pr], ssq);
  }
}

// ---------------- top-3 insertion helper ----------------
__device__ __forceinline__ void ins3(float v, float& a, float& b, float& c) {
  if (v < c) {
    if (v < b) { c = b; if (v < a) { b = a; a = v; } else { b = v; } }
    else { c = v; }
  }
}

// ---------------- MFMA GEMM2: 256x256 8-phase schedule, operand-swapped, fused top-3 ----------------
// A = Ct rows (centroids, M=3328), B = phi rows (pixels, N=GBNP). 512 thr / 8 waves (2Mx4N).
// Per wave: 128 cent x 64 pix = acc[8][4]. LDS 128KB double-buffered; counted-flight staging:
// A-halves staged in phase 1, B-halves in phase 2 (of each K-tile), vmcnt(0) drained once per
// K-tile at phase 4 (loads 2-3 phases old). Raw s_barrier (no implicit vmcnt drain).
#define STG_A(b, h, kofs) \
  gld16(gAp[h][0] + (kofs), &lds[b][0][(h) * 128 + wave * 16][0]); \
  gld16(gAp[h][1] + (kofs), &lds[b][0][(h) * 128 + wave * 16 + 8][0]);
#define STG_B(b, h, kofs) \
  gld16(gBp[h][0] + (kofs), &lds[b][1][(h) * 128 + wave * 16][0]); \
  gld16(gBp[h][1] + (kofs), &lds[b][1][(h) * 128 + wave * 16 + 8][0]);
#define LDA(buf, fi, kk) (*(const short8*)&lds[buf][0][wm * 128 + (fi) * 16 + l15][(((quad) + 4 * (kk)) ^ (l15 & 7)) * 8])
#define LDB(buf, fj, kk) (*(const short8*)&lds[buf][1][wn * 64 + (fj) * 16 + l15][(((quad) + 4 * (kk)) ^ (l15 & 7)) * 8])

__global__ __launch_bounds__(512, 2) void gemm2_mfma(const uint16_t* __restrict__ phi_t, const uint16_t* __restrict__ Ct,
                                                     const float* __restrict__ cent, float* __restrict__ partial,
                                                     int GBNP) {
  __shared__ uint16_t lds[2][2][256][64];   // [buf][A/B][row][col] = 128 KB
  int wid = xcd_swizzle(blockIdx.x, gridDim.x);
  int cb = wid % 13, pb = wid / 13;
  int col0 = cb * 256;               // centroid base
  int row0 = pb * 256;               // pixel base (global incl. group)
  int t = threadIdx.x, lane = t & 63, wave = t >> 6;
  int wm = wave & 1, wn = wave >> 1;
  int l15 = lane & 15, quad = lane >> 4;
  int srow = lane >> 3;
  int sg = ((lane & 7) ^ srow) * 8;
  // staging base pointers: wave w instr i covers rows (h*128 + w*16 + i*8 + srow)
  const uint16_t* gAp[2][2];
  const uint16_t* gBp[2][2];
  #pragma unroll
  for (int h = 0; h < 2; ++h)
    #pragma unroll
    for (int i = 0; i < 2; ++i) {
      int ra = col0 + h * 128 + wave * 16 + i * 8 + srow;            // < 3328 always
      int rb = row0 + h * 128 + wave * 16 + i * 8 + srow;
      rb = rb < GBNP ? rb : GBNP - 1;                                 // clamp (GB odd tail)
      gAp[h][i] = Ct    + (size_t)ra * ODIM + sg;
      gBp[h][i] = phi_t + (size_t)rb * ODIM + sg;
    }
  f32x4 acc[8][4] = {};
  // prologue: stage K-tile 0 into buf0, drain
  STG_A(0, 0, 0) STG_A(0, 1, 0) STG_B(0, 0, 0) STG_B(0, 1, 0)
  asm volatile("s_waitcnt vmcnt(0)" ::: "memory");
  __builtin_amdgcn_s_barrier();
  short8 af[4], bf[4];
  for (int kt = 0; kt < 28; ++kt) {
    int cur = kt & 1, nxt = cur ^ 1;
    int kn = (kt + 1) * 64;
    bool pf = (kt + 1 < 28);
    // ---- phase 1: kk=0, fi 0-3; issue A-half prefetch
    if (pf) { STG_A(nxt, 0, kn) STG_A(nxt, 1, kn) }
    #pragma unroll
    for (int fj = 0; fj < 4; ++fj) bf[fj] = LDB(cur, fj, 0);
    #pragma unroll
    for (int fi = 0; fi < 4; ++fi) af[fi] = LDA(cur, fi, 0);
    __builtin_amdgcn_s_barrier();
    __builtin_amdgcn_s_setprio(1);
    #pragma unroll
    for (int fi = 0; fi < 4; ++fi)
      #pragma unroll
      for (int fj = 0; fj < 4; ++fj)
        acc[fi][fj] = __builtin_amdgcn_mfma_f32_16x16x32_bf16(af[fi], bf[fj], acc[fi][fj], 0, 0, 0);
    __builtin_amdgcn_s_setprio(0);
    __builtin_amdgcn_s_barrier();
    // ---- phase 2: kk=0, fi 4-7; issue B-half prefetch (bf reused)
    if (pf) { STG_B(nxt, 0, kn) STG_B(nxt, 1, kn) }
    #pragma unroll
    for (int fi = 0; fi < 4; ++fi) af[fi] = LDA(cur, fi + 4, 0);
    __builtin_amdgcn_s_barrier();
    __builtin_amdgcn_s_setprio(1);
    #pragma unroll
    for (int fi = 0; fi < 4; ++fi)
      #pragma unroll
      for (int fj = 0; fj < 4; ++fj)
        acc[fi + 4][fj] = __builtin_amdgcn_mfma_f32_16x16x32_bf16(af[fi], bf[fj], acc[fi + 4][fj], 0, 0, 0);
    __builtin_amdgcn_s_setprio(0);
    __builtin_amdgcn_s_barrier();
    // ---- phase 3: kk=1, fi 0-3
    #pragma unroll
    for (int fj = 0; fj < 4; ++fj) bf[fj] = LDB(cur, fj, 1);
    #pragma unroll
    for (int fi = 0; fi < 4; ++fi) af[fi] = LDA(cur, fi, 1);
    __builtin_amdgcn_s_barrier();
    __builtin_amdgcn_s_setprio(1);
    #pragma unroll
    for (int fi = 0; fi < 4; ++fi)
      #pragma unroll
      for (int fj = 0; fj < 4; ++fj)
        acc[fi][fj] = __builtin_amdgcn_mfma_f32_16x16x32_bf16(af[fi], bf[fj], acc[fi][fj], 0, 0, 0);
    __builtin_amdgcn_s_setprio(0);
    __builtin_amdgcn_s_barrier();
    // ---- phase 4: kk=1, fi 4-7; K-tile boundary drain (prefetch now 2-3 phases old)
    #pragma unroll
    for (int fi = 0; fi < 4; ++fi) af[fi] = LDA(cur, fi + 4, 1);
    __builtin_amdgcn_s_barrier();
    __builtin_amdgcn_s_setprio(1);
    #pragma unroll
    for (int fi = 0; fi < 4; ++fi)
      #pragma unroll
      for (int fj = 0; fj < 4; ++fj)
        acc[fi + 4][fj] = __builtin_amdgcn_mfma_f32_16x16x32_bf16(af[fi], bf[fj], acc[fi + 4][fj], 0, 0, 0);
    __builtin_amdgcn_s_setprio(0);
    if (pf) asm volatile("s_waitcnt vmcnt(0)" ::: "memory");
    __builtin_amdgcn_s_barrier();
  }
  // epilogue: centroid c = col0 + wm*128 + fi*16 + quad*4 + r (regs); pixel = row0 + wn*64 + fj*16 + l15
  #pragma unroll
  for (int hbl = 0; hbl < 2; ++hbl) {
    if (col0 + wm * 128 + hbl * 64 < NCENT) {        // wave-uniform mask (64-block granularity)
      int hb = (col0 >> 6) + wm * 2 + hbl;
      float4 cv[4];
      #pragma unroll
      for (int f = 0; f < 4; ++f)
        cv[f] = *(const float4*)&cent[col0 + wm * 128 + (hbl * 4 + f) * 16 + quad * 4];
      #pragma unroll
      for (int fj = 0; fj < 4; ++fj) {
        float t0 = 3.4e38f, t1 = 3.4e38f, t2 = 3.4e38f;
        #pragma unroll
        for (int f = 0; f < 4; ++f) {
          float c4[4] = {cv[f].x, cv[f].y, cv[f].z, cv[f].w};
          #pragma unroll
          for (int r = 0; r < 4; ++r)
            ins3(c4[r] - 2.f * acc[hbl * 4 + f][fj][r], t0, t1, t2);
        }
        #pragma unroll
        for (int m = 16; m < 64; m <<= 1) {
          float u0 = __shfl_xor(t0, m, 64);
          float u1 = __shfl_xor(t1, m, 64);
          float u2 = __shfl_xor(t2, m, 64);
          ins3(u0, t0, t1, t2); ins3(u1, t0, t1, t2); ins3(u2, t0, t1, t2);
        }
        int pix = row0 + wn * 64 + fj * 16 + l15;
        if (quad == 0 && pix < GBNP) {
          float* pp = &partial[((size_t)pix * NHB + hb) * 3];
          pp[0] = t0; pp[1] = t1; pp[2] = t2;
        }
      }
    }
  }
}

// ---------------- final reduce over 49 partials/row + softmin score ----------------
__global__ __launch_bounds__(256) void score_kernel(const float* __restrict__ partial, const float* __restrict__ feat,
                                                    float* __restrict__ out, int g0) {
  int t = threadIdx.x, lane = t & 63, wave = t >> 6;
  int gi = blockIdx.x * 4 + wave;
  int bg = gi / HWo, row = gi - bg * HWo;
  int grow = bg * NP + row;
  float t0 = 3.4e38f, t1 = 3.4e38f, t2 = 3.4e38f;
  if (lane < NHB) {
    const float* pp = &partial[((size_t)grow * NHB + lane) * 3];
    ins3(pp[0], t0, t1, t2); ins3(pp[1], t0, t1, t2); ins3(pp[2], t0, t1, t2);
  }
  #pragma unroll
  for (int m = 1; m < 64; m <<= 1) {
    float u0 = __shfl_xor(t0, m, 64);
    float u1 = __shfl_xor(t1, m, 64);
    float u2 = __shfl_xor(t2, m, 64);
    ins3(u0, t0, t1, t2); ins3(u1, t0, t1, t2); ins3(u2, t0, t1, t2);
  }
  if (lane == 0) {
    float ft = feat[grow];
    float v0 = sqrtf(fmaxf(ft + t0, 0.f));
    float v1 = sqrtf(fmaxf(ft + t1, 0.f));
    float v2 = sqrtf(fmaxf(ft + t2, 0.f));
    float w0 = 1.f / (1.f + expf(v0 - v1) + expf(v0 - v2));
    out[(size_t)(g0 + bg) * HWo + row] = v0 * w0;
  }
}

// ---------------- launch ----------------
extern "C" void kernel_launch(void* const* d_in, const int* in_sizes, int n_in,
                              void* d_out, int out_size, void* d_ws, size_t ws_size,
                              hipStream_t stream) {
  const float* p1   = (const float*)d_in[0];
  const float* p2   = (const float*)d_in[1];
  const float* p3   = (const float*)d_in[2];
  const float* Wm   = (const float*)d_in[3];
  const float* bias = (const float*)d_in[4];
  const float* Cm   = (const float*)d_in[5];
  float* out = (float*)d_out;

  const size_t szWh   = (size_t)ODIM * KP1 * 2;       //  6,651,904
  const size_t szCt   = (size_t)NPC * ODIM * 2;       // 11,927,552 (padded to 3328 rows)
  const size_t szCent = (size_t)NPC * 4;
  const size_t szXcb  = (size_t)NP * KP1 * 2;         // per batch: 11,878,400
  const size_t szPhi  = (size_t)NP * ODIM * 2;        // per batch: 11,468,800 (pooled aliases here)
  const size_t szPart = (size_t)NP * NHB * 3 * 4;     // per batch:  1,881,600
  const size_t szFeat = (size_t)NP * 4;
  const size_t fixedSz = szWh + szCt + szCent;
  const size_t perSz   = szXcb + szPhi + szPart + szFeat;
  int GB = 8;
  while (GB > 1 && fixedSz + perSz * (size_t)GB > ws_size) GB >>= 1;

  char* ws = (char*)d_ws;
  size_t off = 0;
  uint16_t* Wh     = (uint16_t*)(ws + off); off += szWh;
  uint16_t* Ct     = (uint16_t*)(ws + off); off += szCt;
  float*    cent   = (float*)(ws + off);    off += szCent;
  uint16_t* xcb    = (uint16_t*)(ws + off); off += szXcb * GB;
  uint16_t* phi_t  = (uint16_t*)(ws + off);                       // pooled aliases phi region
  float*    pooled = (float*)(ws + off);    off += szPhi * GB;
  float*    partial= (float*)(ws + off);    off += szPart * GB;
  float*    feat   = (float*)(ws + off);    off += szFeat * GB;

  convW_kernel<<<(ODIM * KP1) / 256, 256, 0, stream>>>(Wm, Wh);
  convC_kernel<<<dim3(NCENT / 64, ODIM / 64), 256, 0, stream>>>(Cm, Ct);
  // zero Ct tail rows 3136..3327 (192*1792 u16 = 172032 f32), then row-norms over all 3328 rows
  zerof_kernel<<<672, 256, 0, stream>>>((float*)(Ct + (size_t)NCENT * ODIM), 172032);
  rownorm_kernel<<<NPC / 4, 256, 0, stream>>>(Ct, cent);

  for (int g0 = 0; g0 < NB; g0 += GB) {
    int GBNP = GB * NP;
    int npb = (GBNP + 255) / 256;                     // pixel 256-blocks (exact for even GB)
    pool_kernel<<<dim3(PTOT / 256, GB), 256, 0, stream>>>(p1, p2, p3, pooled, g0);
    assemble_kernel<<<dim3((HWo * KP1) / 256, GB), 256, 0, stream>>>(pooled, xcb);
    zerof_kernel<<<(NP * GB) / 256, 256, 0, stream>>>(feat, NP * GB);
    gemm1_mfma<<<GB * 25 * 14, 256, 0, stream>>>(Wh, bias, xcb, phi_t, feat);
    gemm2_mfma<<<13 * npb, 512, 0, stream>>>(phi_t, Ct, cent, partial, GBNP);
    score_kernel<<<GB * HWo / 4, 256, 0, stream>>>(partial, feat, out, g0);
  }
}

// Round 8
// 993.401 us; speedup vs baseline: 1.2994x; 1.2994x over previous
//
#include <hip/hip_runtime.h>
#include <math.h>
#include <stdint.h>

typedef float f32x4 __attribute__((ext_vector_type(4)));
typedef short short8 __attribute__((ext_vector_type(8)));

static constexpr int HWo   = 3136;   // 56*56
static constexpr int NB    = 8;
static constexpr int NP    = 3200;   // padded pixel / centroid count (25*128)
static constexpr int KDIM  = 1794;   // 1792 + 2 coord channels
static constexpr int KP1   = 1856;   // gemm1 K padded to 29*64
static constexpr int ODIM  = 1792;   // gemm2 K = 28*64
static constexpr int NCENT = 3136;
static constexpr int NHB   = 50;     // 64-col half-blocks per row (NP/64), layout stride
static constexpr int NHBV  = 49;     // valid half-blocks (NCENT/64); hb 49 is all-padding

__device__ __forceinline__ uint16_t f2bf(float f) {
  union { float f; uint32_t u; } v; v.f = f;
  uint32_t u = v.u;
  return (uint16_t)((u + 0x7FFFu + ((u >> 16) & 1u)) >> 16);   // RNE
}
__device__ __forceinline__ float bf2f(uint16_t h) {
  union { uint32_t u; float f; } v; v.u = ((uint32_t)h) << 16;
  return v.f;
}

// async global->LDS, 16B per lane; LDS dest is wave-uniform base + lane*16
__device__ __forceinline__ void gld16(const uint16_t* __restrict__ g, uint16_t* l) {
  __builtin_amdgcn_global_load_lds(
      (const __attribute__((address_space(1))) uint16_t*)g,
      (__attribute__((address_space(3))) uint16_t*)l,
      16, 0, 0);
}

// bijective XCD-chunk swizzle (m204)
__device__ __forceinline__ int xcd_swizzle(int bid, int nwg) {
  int q = nwg >> 3, r = nwg & 7;
  int xcd = bid & 7, idx = bid >> 3;
  int base = (xcd < r) ? xcd * (q + 1) : r * (q + 1) + (xcd - r) * q;
  return base + idx;
}

// ---------------- one-time converts ----------------
__global__ __launch_bounds__(256) void convW_kernel(const float* __restrict__ W, uint16_t* __restrict__ Wh) {
  int idx = blockIdx.x * 256 + threadIdx.x;          // 1792*1856 exact
  int o = idx / KP1, k = idx % KP1;
  float v = (k < KDIM) ? W[(size_t)o * KDIM + k] : 0.f;
  Wh[idx] = f2bf(v);
}

// C [1792][3136] f32 -> Ct [3136][1792] bf16, 64x64 LDS-tiled transpose (both sides coalesced)
__global__ __launch_bounds__(256) void convC_kernel(const float* __restrict__ C, uint16_t* __restrict__ Ct) {
  __shared__ float tile[64][65];
  int bj = blockIdx.x * 64;          // centroid block (49)
  int bo = blockIdx.y * 64;          // channel block  (28)
  int tx = threadIdx.x & 63, ty = threadIdx.x >> 6;
  #pragma unroll
  for (int s = 0; s < 16; ++s) {
    int o = ty + s * 4;
    tile[o][tx] = C[(size_t)(bo + o) * NCENT + bj + tx];
  }
  __syncthreads();
  #pragma unroll
  for (int s = 0; s < 16; ++s) {
    int j = ty + s * 4;
    Ct[(size_t)(bj + j) * ODIM + bo + tx] = f2bf(tile[tx][j]);
  }
}

// ---------------- row squared-norms of a bf16 [*][1792] matrix (Ct -> cent) ----------------
__global__ __launch_bounds__(256) void rownorm_kernel(const uint16_t* __restrict__ src, float* __restrict__ dst) {
  int t = threadIdx.x, lane = t & 63, wave = t >> 6;
  int row = blockIdx.x * 4 + wave;
  const uint32_t* p = (const uint32_t*)(src + (size_t)row * ODIM);
  float s = 0.f;
  #pragma unroll
  for (int it = 0; it < 14; ++it) {
    uint32_t u = p[it * 64 + lane];
    float a = bf2f((uint16_t)(u & 0xFFFF)), b = bf2f((uint16_t)(u >> 16));
    s += a * a + b * b;
  }
  #pragma unroll
  for (int m = 1; m < 64; m <<= 1) s += __shfl_xor(s, m, 64);
  if (lane == 0) dst[row] = s;
}

// ---------------- zero-fill (graph-capture-safe) ----------------
__global__ __launch_bounds__(256) void zerof_kernel(float* __restrict__ p, int n) {
  int i = blockIdx.x * 256 + threadIdx.x;
  if (i < n) p[i] = 0.f;
}

// ---------------- pooling (all 3 levels, native res, fp32), batched on blockIdx.y ----------------
static constexpr int P1SZ = 256 * 3136;   // 802816
static constexpr int P2SZ = 512 * 784;    // 401408
static constexpr int P3SZ = 1024 * 196;   // 200704
static constexpr int PTOT = P1SZ + P2SZ + P3SZ;      // 1404928

__device__ __forceinline__ float pool9f(const float* __restrict__ p, int S, int y, int x) {
  float s = 0.f;
  for (int dy = -1; dy <= 1; ++dy) {
    int yy = y + dy; if (yy < 0 || yy >= S) continue;
    for (int dx = -1; dx <= 1; ++dx) {
      int xx = x + dx; if (xx < 0 || xx >= S) continue;
      s += p[yy * S + xx];
    }
  }
  return s * (1.f / 9.f);
}

__global__ __launch_bounds__(256) void pool_kernel(const float* __restrict__ p1, const float* __restrict__ p2,
                                                   const float* __restrict__ p3, float* __restrict__ pooled, int g0) {
  int b = g0 + blockIdx.y;
  float* pb = pooled + (size_t)blockIdx.y * PTOT;
  int idx = blockIdx.x * 256 + threadIdx.x;
  const float* src; int S, loc;
  if (idx < P1SZ)              { src = p1 + (size_t)b * P1SZ; S = 56; loc = idx; }
  else if (idx < P1SZ + P2SZ)  { src = p2 + (size_t)b * P2SZ; S = 28; loc = idx - P1SZ; }
  else                         { src = p3 + (size_t)b * P3SZ; S = 14; loc = idx - P1SZ - P2SZ; }
  int c = loc / (S * S), hw = loc % (S * S);
  pb[idx] = pool9f(src + (size_t)c * S * S, S, hw / S, hw % S);
}

// ---------------- assemble, coalesced 3-kernel version ----------------
// asmA: L1 channels 0..255 = [ch][pix] -> [pix][ch] 64x64 LDS-tiled transpose
__global__ __launch_bounds__(256) void asmA_kernel(const float* __restrict__ pooled, uint16_t* __restrict__ xcb) {
  __shared__ float tile[64][65];
  int bg = blockIdx.z;
  const float* pb = pooled + (size_t)bg * PTOT;
  uint16_t* xb = xcb + (size_t)bg * NP * KP1;
  int p0 = blockIdx.x * 64;          // pixel tile (49)
  int c0 = blockIdx.y * 64;          // channel tile (4)
  int tx = threadIdx.x & 63, ty = threadIdx.x >> 6;
  #pragma unroll
  for (int s = 0; s < 16; ++s) {
    int c = ty + s * 4;
    tile[c][tx] = pb[(size_t)(c0 + c) * HWo + p0 + tx];
  }
  __syncthreads();
  #pragma unroll
  for (int s = 0; s < 16; ++s) {
    int p = ty + s * 4;
    xb[(size_t)(p0 + p) * KP1 + c0 + tx] = f2bf(tile[tx][p]);
  }
}

// asmB: bilinear channels 256..1791. One block = (y, 128-channel tile of one level).
// Source rows y0,y1 for all 128 channels staged in LDS (coalesced reads), stride-29 pad.
__global__ __launch_bounds__(256) void asmB_kernel(const float* __restrict__ pooled, uint16_t* __restrict__ xcb) {
  __shared__ float rows[2][128][29];
  int bg = blockIdx.z;
  const float* pb = pooled + (size_t)bg * PTOT;
  uint16_t* xb = xcb + (size_t)bg * NP * KP1;
  int y = blockIdx.x;                // 0..55
  int ct = blockIdx.y;               // 0..11 (0-3: L2, 4-11: L3)
  bool lvl2 = ct < 4;
  int S = lvl2 ? 28 : 14;
  float scale = lvl2 ? 0.5f : 0.25f;
  float shift = lvl2 ? -0.25f : -0.375f;
  int chbase = lvl2 ? 256 + ct * 128 : 768 + (ct - 4) * 128;
  const float* base = lvl2 ? pb + P1SZ + (size_t)(ct * 128) * 784
                           : pb + P1SZ + P2SZ + (size_t)((ct - 4) * 128) * 196;
  int planesz = S * S;
  float sy = y * scale + shift;
  float fy0 = floorf(sy);
  float fy = sy - fy0;
  int y0 = (int)fy0, y1 = y0 + 1;
  y0 = y0 < 0 ? 0 : y0; y1 = y1 > S - 1 ? S - 1 : y1;
  int t = threadIdx.x;
  int tot = 128 * 2 * S;
  for (int idx = t; idx < tot; idx += 256) {
    int r = idx / S, e = idx - r * S;       // r = c*2 + yr, coalesced within each S-run
    int c = r >> 1, yr = r & 1;
    rows[yr][c][e] = base[(size_t)c * planesz + (yr ? y1 : y0) * S + e];
  }
  __syncthreads();
  int c = t & 127, xs = t >> 7;
  #pragma unroll
  for (int xi = 0; xi < 28; ++xi) {
    int x = xi * 2 + xs;
    float sx = x * scale + shift;
    float fx0 = floorf(sx);
    float fx = sx - fx0;
    int x0 = (int)fx0, x1 = x0 + 1;
    x0 = x0 < 0 ? 0 : x0; x1 = x1 > S - 1 ? S - 1 : x1;
    float v00 = rows[0][c][x0], v01 = rows[0][c][x1];
    float v10 = rows[1][c][x0], v11 = rows[1][c][x1];
    float v = (1.f - fy) * ((1.f - fx) * v00 + fx * v01) + fy * ((1.f - fx) * v10 + fx * v11);
    xb[(size_t)(y * 56 + x) * KP1 + chbase + c] = f2bf(v);
  }
}

// asmC: coord channels 1792/1793 + zero K-padding 1794..1855
__global__ __launch_bounds__(256) void asmC_kernel(uint16_t* __restrict__ xcb) {
  int bg = blockIdx.y;
  uint16_t* xb = xcb + (size_t)bg * NP * KP1;
  int idx = blockIdx.x * 256 + threadIdx.x;          // 3136*64 exact
  int i = idx >> 6, ch = 1792 + (idx & 63);
  int x = i % 56, y = i / 56;
  float v = (ch == 1792) ? (-1.f + 2.f * x / 55.f)
          : (ch == 1793) ? (-1.f + 2.f * y / 55.f) : 0.f;
  xb[(size_t)i * KP1 + ch] = f2bf(v);
}

// ---------------- MFMA GEMM1 (m97 2-barrier) + LDS-transpose epilogue + fused rownorm ----------------
__global__ __launch_bounds__(256) void gemm1_mfma(const uint16_t* __restrict__ Wh, const float* __restrict__ bias,
                                                  const uint16_t* __restrict__ xcb, uint16_t* __restrict__ phi_t,
                                                  float* __restrict__ feat) {
  __shared__ union { uint16_t ab[2][128][64]; uint16_t tr[128][136]; } sm;
  int wid = xcd_swizzle(blockIdx.x, gridDim.x);
  int row0 = (wid % 14) * 128;       // o block (fast axis)
  int col0 = (wid / 14) * 128;       // pixel block (global incl. group)
  int t = threadIdx.x;
  int lane = t & 63, wave = t >> 6;
  int wm = wave & 1, wn = wave >> 1;
  int l15 = lane & 15, quad = lane >> 4;
  int rr = wave * 8 + (lane >> 3);
  int sg = ((lane & 7) ^ (lane >> 3)) * 8;
  f32x4 acc[4][4] = {};
  for (int k0 = 0; k0 < KP1; k0 += 64) {
    #pragma unroll
    for (int i = 0; i < 4; ++i) {
      gld16(&Wh [(size_t)(row0 + i * 32 + rr) * KP1 + k0 + sg], &sm.ab[0][i * 32 + wave * 8][0]);
      gld16(&xcb[(size_t)(col0 + i * 32 + rr) * KP1 + k0 + sg], &sm.ab[1][i * 32 + wave * 8][0]);
    }
    __syncthreads();
    #pragma unroll
    for (int kk = 0; kk < 2; ++kk) {
      short8 a[4], b[4];
      #pragma unroll
      for (int i = 0; i < 4; ++i) {
        int r = wm * 64 + i * 16 + l15;
        a[i] = *(const short8*)&sm.ab[0][r][((quad + 4 * kk) ^ (r & 7)) * 8];
      }
      #pragma unroll
      for (int j = 0; j < 4; ++j) {
        int r = wn * 64 + j * 16 + l15;
        b[j] = *(const short8*)&sm.ab[1][r][((quad + 4 * kk) ^ (r & 7)) * 8];
      }
      #pragma unroll
      for (int i = 0; i < 4; ++i)
        #pragma unroll
        for (int j = 0; j < 4; ++j)
          acc[i][j] = __builtin_amdgcn_mfma_f32_16x16x32_bf16(a[i], b[j], acc[i][j], 0, 0, 0);
    }
    __syncthreads();
  }
  #pragma unroll
  for (int i = 0; i < 4; ++i) {
    int o4 = wm * 64 + i * 16 + quad * 4;
    float4 bv = *(const float4*)&bias[row0 + o4];
    #pragma unroll
    for (int j = 0; j < 4; ++j) {
      int p = wn * 64 + j * 16 + l15;
      ushort4 u;
      u.x = f2bf(acc[i][j][0] + bv.x);
      u.y = f2bf(acc[i][j][1] + bv.y);
      u.z = f2bf(acc[i][j][2] + bv.z);
      u.w = f2bf(acc[i][j][3] + bv.w);
      *(ushort4*)&sm.tr[p][o4] = u;
    }
  }
  __syncthreads();
  int c = t & 15, prb = t >> 4;
  #pragma unroll
  for (int s = 0; s < 8; ++s) {
    int pr = s * 16 + prb;
    uint4 v = *(const uint4*)&sm.tr[pr][c * 8];
    *(uint4*)&phi_t[(size_t)(col0 + pr) * ODIM + row0 + c * 8] = v;
    const uint16_t* pv = (const uint16_t*)&v;
    float ssq = 0.f;
    #pragma unroll
    for (int e = 0; e < 8; ++e) { float f = bf2f(pv[e]); ssq += f * f; }
    #pragma unroll
    for (int m = 1; m < 16; m <<= 1) ssq += __shfl_xor(ssq, m, 16);
    if (c == 0) atomicAdd(&feat[col0 + pr], ssq);
  }
}

// ---------------- top-3 insertion helper ----------------
__device__ __forceinline__ void ins3(float v, float& a, float& b, float& c) {
  if (v < c) {
    if (v < b) { c = b; if (v < a) { b = a; a = v; } else { b = v; } }
    else { c = v; }
  }
}

// ---------------- MFMA GEMM2, operand-SWAPPED + fused per-64col partial top-3 (round-6 proven) ----------------
__global__ __launch_bounds__(256) void gemm2_mfma(const uint16_t* __restrict__ phi_t, const uint16_t* __restrict__ Ct,
                                                  const float* __restrict__ cent, float* __restrict__ partial) {
  __shared__ uint16_t As[128][64];   // phi rows (pixels row0..row0+128)
  __shared__ uint16_t Bs[128][64];   // Ct rows (centroids col0..col0+128)
  int wid = xcd_swizzle(blockIdx.x, gridDim.x);
  int col0 = (wid % 25) * 128;       // centroid base (fast axis)
  int row0 = (wid / 25) * 128;       // pixel base (global incl. group)
  int t = threadIdx.x;
  int lane = t & 63, wave = t >> 6;
  int wc = wave & 1;                 // centroid 64-half of the block
  int wp = wave >> 1;                // pixel 64-half of the block
  int l15 = lane & 15, quad = lane >> 4;
  int rr = wave * 8 + (lane >> 3);
  int sg = ((lane & 7) ^ (lane >> 3)) * 8;
  f32x4 acc[4][4] = {};              // acc[i=centroid frag][j=pixel frag]
  for (int k0 = 0; k0 < ODIM; k0 += 64) {
    #pragma unroll
    for (int i = 0; i < 4; ++i) {
      gld16(&phi_t[(size_t)(row0 + i * 32 + rr) * ODIM + k0 + sg], &As[i * 32 + wave * 8][0]);
      gld16(&Ct   [(size_t)(col0 + i * 32 + rr) * ODIM + k0 + sg], &Bs[i * 32 + wave * 8][0]);
    }
    __syncthreads();
    #pragma unroll
    for (int kk = 0; kk < 2; ++kk) {
      short8 ac[4], bp[4];
      #pragma unroll
      for (int i = 0; i < 4; ++i) {          // A-operand: centroid fragments from Ct
        int r = wc * 64 + i * 16 + l15;
        ac[i] = *(const short8*)&Bs[r][((quad + 4 * kk) ^ (r & 7)) * 8];
      }
      #pragma unroll
      for (int j = 0; j < 4; ++j) {          // B-operand: pixel fragments from phi
        int r = wp * 64 + j * 16 + l15;
        bp[j] = *(const short8*)&As[r][((quad + 4 * kk) ^ (r & 7)) * 8];
      }
      #pragma unroll
      for (int i = 0; i < 4; ++i)
        #pragma unroll
        for (int j = 0; j < 4; ++j)
          acc[i][j] = __builtin_amdgcn_mfma_f32_16x16x32_bf16(ac[i], bp[j], acc[i][j], 0, 0, 0);
    }
    __syncthreads();
  }
  if (col0 + wc * 64 < NCENT) {
    float4 cv[4];
    #pragma unroll
    for (int i = 0; i < 4; ++i)
      cv[i] = *(const float4*)&cent[col0 + wc * 64 + i * 16 + quad * 4];
    int hb = (col0 >> 6) + wc;
    #pragma unroll
    for (int j = 0; j < 4; ++j) {
      float t0 = 3.4e38f, t1 = 3.4e38f, t2 = 3.4e38f;
      #pragma unroll
      for (int i = 0; i < 4; ++i) {
        float c4[4] = {cv[i].x, cv[i].y, cv[i].z, cv[i].w};
        #pragma unroll
        for (int r = 0; r < 4; ++r)
          ins3(c4[r] - 2.f * acc[i][j][r], t0, t1, t2);
      }
      #pragma unroll
      for (int m = 16; m < 64; m <<= 1) {
        float u0 = __shfl_xor(t0, m, 64);
        float u1 = __shfl_xor(t1, m, 64);
        float u2 = __shfl_xor(t2, m, 64);
        ins3(u0, t0, t1, t2); ins3(u1, t0, t1, t2); ins3(u2, t0, t1, t2);
      }
      if (quad == 0) {
        int pix = row0 + wp * 64 + j * 16 + l15;
        float* pp = &partial[((size_t)pix * NHB + hb) * 3];
        pp[0] = t0; pp[1] = t1; pp[2] = t2;
      }
    }
  }
}

// ---------------- final reduce over 49 valid partials/row + softmin score ----------------
__global__ __launch_bounds__(256) void score_kernel(const float* __restrict__ partial, const float* __restrict__ feat,
                                                    float* __restrict__ out, int g0) {
  int t = threadIdx.x, lane = t & 63, wave = t >> 6;
  int gi = blockIdx.x * 4 + wave;
  int bg = gi / HWo, row = gi - bg * HWo;
  int grow = bg * NP + row;
  float t0 = 3.4e38f, t1 = 3.4e38f, t2 = 3.4e38f;
  if (lane < NHBV) {
    const float* pp = &partial[((size_t)grow * NHB + lane) * 3];
    ins3(pp[0], t0, t1, t2); ins3(pp[1], t0, t1, t2); ins3(pp[2], t0, t1, t2);
  }
  #pragma unroll
  for (int m = 1; m < 64; m <<= 1) {
    float u0 = __shfl_xor(t0, m, 64);
    float u1 = __shfl_xor(t1, m, 64);
    float u2 = __shfl_xor(t2, m, 64);
    ins3(u0, t0, t1, t2); ins3(u1, t0, t1, t2); ins3(u2, t0, t1, t2);
  }
  if (lane == 0) {
    float ft = feat[grow];
    float v0 = sqrtf(fmaxf(ft + t0, 0.f));
    float v1 = sqrtf(fmaxf(ft + t1, 0.f));
    float v2 = sqrtf(fmaxf(ft + t2, 0.f));
    float w0 = 1.f / (1.f + expf(v0 - v1) + expf(v0 - v2));
    out[(size_t)(g0 + bg) * HWo + row] = v0 * w0;
  }
}

// ---------------- launch ----------------
extern "C" void kernel_launch(void* const* d_in, const int* in_sizes, int n_in,
                              void* d_out, int out_size, void* d_ws, size_t ws_size,
                              hipStream_t stream) {
  const float* p1   = (const float*)d_in[0];
  const float* p2   = (const float*)d_in[1];
  const float* p3   = (const float*)d_in[2];
  const float* Wm   = (const float*)d_in[3];
  const float* bias = (const float*)d_in[4];
  const float* Cm   = (const float*)d_in[5];
  float* out = (float*)d_out;

  const size_t szWh   = (size_t)ODIM * KP1 * 2;       //  6,651,904
  const size_t szCt   = (size_t)NP * ODIM * 2;        // 11,468,800
  const size_t szCent = (size_t)NP * 4;
  const size_t szXcb  = (size_t)NP * KP1 * 2;         // per batch: 11,878,400
  const size_t szPhi  = (size_t)NP * ODIM * 2;        // per batch: 11,468,800 (pooled aliases here)
  const size_t szPart = (size_t)NP * NHB * 3 * 4;     // per batch:  1,920,000
  const size_t szFeat = (size_t)NP * 4;
  const size_t fixedSz = szWh + szCt + szCent;
  const size_t perSz   = szXcb + szPhi + szPart + szFeat;
  int GB = 8;
  while (GB > 1 && fixedSz + perSz * (size_t)GB > ws_size) GB >>= 1;

  char* ws = (char*)d_ws;
  size_t off = 0;
  uint16_t* Wh     = (uint16_t*)(ws + off); off += szWh;
  uint16_t* Ct     = (uint16_t*)(ws + off); off += szCt;
  float*    cent   = (float*)(ws + off);    off += szCent;
  uint16_t* xcb    = (uint16_t*)(ws + off); off += szXcb * GB;
  uint16_t* phi_t  = (uint16_t*)(ws + off);                       // pooled aliases phi region
  float*    pooled = (float*)(ws + off);    off += szPhi * GB;
  float*    partial= (float*)(ws + off);    off += szPart * GB;
  float*    feat   = (float*)(ws + off);    off += szFeat * GB;

  convW_kernel<<<(ODIM * KP1) / 256, 256, 0, stream>>>(Wm, Wh);
  convC_kernel<<<dim3(NCENT / 64, ODIM / 64), 256, 0, stream>>>(Cm, Ct);
  rownorm_kernel<<<784, 256, 0, stream>>>(Ct, cent);

  for (int g0 = 0; g0 < NB; g0 += GB) {
    pool_kernel<<<dim3(PTOT / 256, GB), 256, 0, stream>>>(p1, p2, p3, pooled, g0);
    asmA_kernel<<<dim3(HWo / 64, 4, GB), 256, 0, stream>>>(pooled, xcb);
    asmB_kernel<<<dim3(56, 12, GB), 256, 0, stream>>>(pooled, xcb);
    asmC_kernel<<<dim3((HWo * 64) / 256, GB), 256, 0, stream>>>(xcb);
    zerof_kernel<<<(NP * GB) / 256, 256, 0, stream>>>(feat, NP * GB);
    gemm1_mfma<<<GB * 25 * 14, 256, 0, stream>>>(Wh, bias, xcb, phi_t, feat);
    gemm2_mfma<<<GB * 25 * 25, 256, 0, stream>>>(phi_t, Ct, cent, partial);
    score_kernel<<<GB * HWo / 4, 256, 0, stream>>>(partial, feat, out, g0);
  }
}